// Round 1
// baseline (721.686 us; speedup 1.0000x reference)
//
#include <hip/hip_runtime.h>
#include <hip/hip_cooperative_groups.h>

namespace cgx = cooperative_groups;

static constexpr int NN  = 6144;
static constexpr int NE  = 98304;
static constexpr int NF  = 128;
static constexpr int NT  = 16;
static constexpr int MN  = 10;
static constexpr int NCG = 5;
static constexpr int NSK = 50;
static constexpr int WPR = NN / 32;
static constexpr int TPB = 768;
static constexpr int NBLK = 256;
static constexpr int RPT = NN / TPB;   // 8 rows/thread
static constexpr int NW  = TPB / 64;   // 12 waves

static_assert(TPB * RPT == NN, "row mapping");

// workspace layout (float elements); BM (setup-only) aliases T+C+D region
static constexpr size_t OFF_M   = 0;                              // fp32 [NT][NN][10]
static constexpr size_t OFF_T   = OFF_M  + (size_t)NT * NN * MN;  // u32 bf16-pairs [NT][NN][5]
static constexpr size_t OFF_C   = OFF_T  + (size_t)NT * NN * 5;
static constexpr size_t OFF_D   = OFF_C  + (size_t)NT * NN * 5;
static constexpr size_t OFF_RS  = OFF_D  + (size_t)NT * NN * 5;
static constexpr size_t OFF_DEG = OFF_RS + NN;
static constexpr size_t OFF_CI  = OFF_DEG + NN;                   // ushort[2*NE] in NE floats
static constexpr size_t OFF_NNZ = OFF_CI + NE;
static constexpr size_t OFF_HIST= OFF_NNZ + 1;                    // int[256] degree histogram
static constexpr size_t OFF_PERM= OFF_HIST + 256;                 // int[NN] degree-sorted rows

// LDS: dd planes as uint4 (cols 0-7) + u32 (cols 8-9); packed reduction buffer
static constexpr int LDS_PL  = NN * 20;          // 122880 B (dd only now; E lives in regs)
static constexpr int LDS_SP  = TPB * 7 * 4;      // 21504 B (stride 7: conflict-free)
static constexpr int LDS_DYN = LDS_PL + LDS_SP;  // 144384 B

__device__ __forceinline__ unsigned f2bf(float f) {            // fp32 -> bf16 (rne)
    unsigned u = __float_as_uint(f);
    return (u + 0x7fffu + ((u >> 16) & 1u)) >> 16;
}
__device__ __forceinline__ unsigned packbf(float a, float b) { return f2bf(a) | (f2bf(b) << 16); }
__device__ __forceinline__ float bflo(unsigned w) { return __uint_as_float(w << 16); }
__device__ __forceinline__ float bfhi(unsigned w) { return __uint_as_float(w & 0xffff0000u); }

extern __shared__ char sMem[];

__global__ __launch_bounds__(TPB) void tfgw_kernel(
    const float* __restrict__ x, const void* __restrict__ eiv,
    const float* __restrict__ tpl, const float* __restrict__ tf,
    const float* __restrict__ q0, const float* __restrict__ a0,
    float* __restrict__ out, float* __restrict__ W)
{
    __shared__ float sC2[MN * MN];
    __shared__ float sq[MN], scq[MN], sqC2[MN], sNSQ[MN];
    __shared__ unsigned svp[5];        // v packed bf16-pairs (row threads read this)
    __shared__ float sVf[MN];          // v fp32 (reducer lanes only: convergence test)
    __shared__ float sCv[5];
    __shared__ float sRed[3 * NW];
    __shared__ float sBC[2];
    __shared__ float sDots[4];
    __shared__ int   sBin[256];        // block 0: counting-sort offsets

    const int tid = threadIdx.x;
    const int bid = blockIdx.x;

    unsigned* BM    = (unsigned*)(W + OFF_T);   // aliased; dead after setup
    int* rowst      = (int*)(W + OFF_RS);
    int* degi       = (int*)(W + OFF_DEG);
    unsigned short* colix = (unsigned short*)(W + OFF_CI);
    int* nnzc       = (int*)(W + OFF_NNZ);
    int* histg      = (int*)(W + OFF_HIST);
    int* permg      = (int*)(W + OFF_PERM);
    float* Mw  = W + OFF_M;
    unsigned* Tg = (unsigned*)(W + OFF_T);
    unsigned* Cg = (unsigned*)(W + OFF_C);
    unsigned* Dg = (unsigned*)(W + OFF_D);

    uint4*    PL4x = (uint4*)sMem;                        // [NN]: dd cols 0-7
    unsigned* PL1x = (unsigned*)(sMem + NN * 16);         // [NN]: dd cols 8-9
    unsigned* sPp  = (unsigned*)(sMem + LDS_PL);          // [TPB*7] packed partials

    const float alpha  = 1.f / (1.f + __expf(-a0[0]));
    const float invn   = 1.f / (float)NN;
    const float alpha2 = 2.f * alpha;
    const float oma    = 1.f - alpha;

    cgx::grid_group grid = cgx::this_grid();

    // ---- P0: zero bitmap + nnz + degree histogram ----
    for (int idx = bid * TPB + tid; idx < NN * WPR; idx += NBLK * TPB) BM[idx] = 0u;
    if (bid == 0) {
        if (tid < 256) histg[tid] = 0;
        if (tid == 0)  *nnzc = 0;
    }
    grid.sync();

    // ---- P1: adjacency bits + feature cost M (sTF overlays sMem) ----
    {
        const unsigned* uw = (const unsigned*)eiv;
        const bool is64 = (uw[1] == 0u && uw[3] == 0u && uw[5] == 0u);
        for (int e = bid * TPB + tid; e < NE; e += NBLK * TPB) {
            int s, d;
            if (is64) {
                s = (int)((const long long*)eiv)[e];
                d = (int)((const long long*)eiv)[NE + e];
            } else {
                s = ((const int*)eiv)[e];
                d = ((const int*)eiv)[NE + e];
            }
            atomicOr(&BM[(size_t)s * WPR + (d >> 5)], 1u << (d & 31));
            atomicOr(&BM[(size_t)d * WPR + (s >> 5)], 1u << (s & 31));
        }
        float* sTF = (float*)sMem;
        const int t = bid >> 4, rb = bid & 15;
        for (int k = tid; k < MN * NF; k += TPB) sTF[k] = tf[t * MN * NF + k];
        __syncthreads();
        if (tid < MN) {
            float s = 0.f;
            for (int k = 0; k < NF; ++k) { float v = sTF[tid * NF + k]; s += v * v; }
            sNSQ[tid] = s;
        }
        __syncthreads();
        if (tid < 384) {
            const int i = rb * 384 + tid;
            const float4* x4 = (const float4*)(x + (size_t)i * NF);
            const float4* t4 = (const float4*)sTF;
            float acc[MN]; float xn = 0.f;
            #pragma unroll
            for (int j = 0; j < MN; ++j) acc[j] = 0.f;
            for (int k4 = 0; k4 < NF / 4; ++k4) {
                float4 xv = x4[k4];
                xn += xv.x * xv.x + xv.y * xv.y + xv.z * xv.z + xv.w * xv.w;
                #pragma unroll
                for (int j = 0; j < MN; ++j) {
                    float4 tv = t4[j * (NF / 4) + k4];
                    acc[j] += xv.x * tv.x + xv.y * tv.y + xv.z * tv.z + xv.w * tv.w;
                }
            }
            float* Mrow = Mw + (size_t)t * NN * MN + (size_t)i * MN;
            #pragma unroll
            for (int j = 0; j < MN; ++j) Mrow[j] = xn + sNSQ[j] - 2.f * acc[j];
        }
    }
    grid.sync();

    // ---- P2: degrees + CSR (ushort cols) + degree histogram ----
    {
        const int i = bid * TPB + tid;
        if (i < NN) {
            int cnt = 0;
            for (int w = 0; w < WPR; ++w) cnt += __popc(BM[(size_t)i * WPR + w]);
            int st = atomicAdd(nnzc, cnt);
            rowst[i] = st; degi[i] = cnt;
            atomicAdd(&histg[cnt > 255 ? 255 : cnt], 1);
            int p = st;
            for (int w = 0; w < WPR; ++w) {
                unsigned m = BM[(size_t)i * WPR + w];
                while (m) { int b = __ffs(m) - 1; m &= m - 1; colix[p++] = (unsigned short)((w << 5) + b); }
            }
        }
    }
    grid.sync();

    // ---- P2b: degree-sorted permutation via counting sort (block 0 only) ----
    // SpMM waves then process equal-degree rows: max(deg) over wave ~= mean(deg),
    // killing the ~45% divergence waste of the dynamic neighbor loop.
    if (bid == 0) {
        if (tid == 0) {
            int run = 0;
            for (int b = 0; b < 256; ++b) { sBin[b] = run; run += histg[b]; }
        }
        __syncthreads();
        for (int i = tid; i < NN; i += TPB) {
            int d = degi[i]; if (d > 255) d = 255;
            permg[atomicAdd(&sBin[d], 1)] = i;
        }
    }
    grid.sync();     // last grid sync

    if (bid >= NT) return;

    // ================= block t owns template t =================
    const int t = bid;
    float* Mb = Mw + (size_t)t * NN * MN;
    unsigned* Tb = Tg + (size_t)t * NN * 5;
    unsigned* Cb = Cg + (size_t)t * NN * 5;
    unsigned* Db = Dg + (size_t)t * NN * 5;

    if (tid == 0) {
        float qv[MN]; float qm = -1e30f;
        for (int j = 0; j < MN; ++j) { qv[j] = q0[t * MN + j]; qm = fmaxf(qm, qv[j]); }
        float qs = 0.f;
        for (int j = 0; j < MN; ++j) { qv[j] = __expf(qv[j] - qm); qs += qv[j]; }
        for (int j = 0; j < MN; ++j) { qv[j] /= qs; sq[j] = qv[j]; }
        for (int j = 0; j < MN; ++j) {
            float s2 = 0.f, s1 = 0.f;
            for (int k = 0; k < MN; ++k) {
                float cjk = tpl[t * MN * MN + j * MN + k];
                s2 += cjk * cjk * qv[k];
                s1 += tpl[t * MN * MN + k * MN + j] * qv[k];
            }
            scq[j] = s2; sqC2[j] = s1;
        }
    }
    for (int k = tid; k < MN * MN; k += TPB) sC2[k] = tpl[t * MN * MN + k];
    __syncthreads();

    // per-thread persistent state: E (or g, in place) fp32 in regs; u; deg/n
    float E[RPT][MN];
    float uu[RPT];
    float cp_[RPT];
    #pragma unroll
    for (int k = 0; k < RPT; ++k) cp_[k] = (float)degi[tid + k * TPB] * invn;

    for (int cgi = 0; cgi < NCG; ++cgi) {
        // ---- tau from previous dots; tau==0 (cgi>0) => fixed point ----
        if (tid == 0) {
            float tau = 0.f;
            if (cgi > 0) {
                float a = -2.f * alpha * sDots[3];
                float b = oma * sDots[0] + alpha * (sDots[1] - 4.f * sDots[2]);
                if (a > 0.f) tau = fminf(fmaxf(-b / (2.f * a + 1e-16f), 0.f), 1.f);
                else         tau = (a + b < 0.f) ? 1.f : 0.f;
            }
            sBC[0] = tau;
        }
        __syncthreads();
        const float tau = sBC[0];
        if (cgi > 0 && tau == 0.f) break;

        // ---- Phase A: update T,C (bf16 globals; dd from planes); g -> regs ----
        float gmax = 0.f;
        #pragma unroll
        for (int k = 0; k < RPT; ++k) {
            const int r = tid + k * TPB;
            const float cp = cp_[k];
            const size_t b5 = (size_t)r * 5;
            float C[MN];
            if (cgi == 0) {
                #pragma unroll
                for (int h = 0; h < 5; ++h) {
                    unsigned tw = packbf(sq[2*h] * invn, sq[2*h+1] * invn);
                    unsigned cw = packbf(cp * sqC2[2*h], cp * sqC2[2*h+1]);
                    Tb[b5 + h] = tw; Cb[b5 + h] = cw;
                    C[2*h] = bflo(cw); C[2*h+1] = bfhi(cw);
                }
            } else {
                float dd[MN];
                uint4 a4 = PL4x[r]; unsigned b4 = PL1x[r];
                dd[0]=bflo(a4.x); dd[1]=bfhi(a4.x); dd[2]=bflo(a4.y); dd[3]=bfhi(a4.y);
                dd[4]=bflo(a4.z); dd[5]=bfhi(a4.z); dd[6]=bflo(a4.w); dd[7]=bfhi(a4.w);
                dd[8]=bflo(b4);   dd[9]=bfhi(b4);
                #pragma unroll
                for (int h = 0; h < 5; ++h) {
                    unsigned tw = Tb[b5 + h], cw = Cb[b5 + h], Dw = Db[b5 + h];
                    float T0 = bflo(tw) + tau * dd[2*h];
                    float T1 = bfhi(tw) + tau * dd[2*h+1];
                    float C0 = bflo(cw) + tau * bflo(Dw);
                    float C1v = bfhi(cw) + tau * bfhi(Dw);
                    unsigned ntw = packbf(T0, T1), ncw = packbf(C0, C1v);
                    Tb[b5 + h] = ntw; Cb[b5 + h] = ncw;
                    C[2*h] = bflo(ncw); C[2*h+1] = bfhi(ncw);
                }
            }
            #pragma unroll
            for (int h = 0; h < 5; ++h) {
                float2 mv = *(const float2*)(Mb + (size_t)r * MN + 2*h);
                float g0 = oma * mv.x + alpha2 * (cp + scq[2*h]   - 2.f * C[2*h]);
                float g1 = oma * mv.y + alpha2 * (cp + scq[2*h+1] - 2.f * C[2*h+1]);
                E[k][2*h] = g0; E[k][2*h+1] = g1;
                gmax = fmaxf(gmax, fmaxf(__builtin_fabsf(g0), __builtin_fabsf(g1)));
            }
        }
        #pragma unroll
        for (int d = 32; d; d >>= 1) gmax = fmaxf(gmax, __shfl_xor(gmax, d));
        if ((tid & 63) == 0) sRed[tid >> 6] = gmax;
        __syncthreads();
        if (tid == 0) {
            float m = sRed[0];
            for (int w = 1; w < NW; ++w) m = fmaxf(m, sRed[w]);
            sBC[1] = 1.f / (0.05f * m + 1e-8f);
        }
        __syncthreads();
        const float invreg = sBC[1];

        // ---- Phase B (merged): E = exp(-g*invreg) in registers ----
        #pragma unroll
        for (int k = 0; k < RPT; ++k)
            #pragma unroll
            for (int j = 0; j < MN; ++j)
                E[k][j] = __expf(-E[k][j] * invreg);

        // ---- Sinkhorn iter 0 (u = 1) — only for cgi==0; else warm-start from prev v ----
        if (cgi == 0) {
            float a[MN];
            #pragma unroll
            for (int j = 0; j < MN; ++j) a[j] = 0.f;
            #pragma unroll
            for (int k = 0; k < RPT; ++k)
                #pragma unroll
                for (int j = 0; j < MN; ++j) a[j] += E[k][j];
            #pragma unroll
            for (int p = 0; p < 5; ++p) sPp[tid * 7 + p] = packbf(a[2*p], a[2*p+1]);
            __syncthreads();
            if (tid < 320) {
                const int p = tid >> 6, c = tid & 63;
                float s0 = 0.f, s1 = 0.f;
                #pragma unroll
                for (int kk = 0; kk < NW; ++kk) {
                    unsigned w = sPp[(c + (kk << 6)) * 7 + p];
                    s0 += bflo(w); s1 += bfhi(w);
                }
                #pragma unroll
                for (int d = 32; d; d >>= 1) { s0 += __shfl_xor(s0, d); s1 += __shfl_xor(s1, d); }
                if (c == 0) {
                    float v0 = sq[2*p] / s0, v1 = sq[2*p+1] / s1;
                    svp[p] = packbf(v0, v1);
                    sVf[2*p] = v0; sVf[2*p+1] = v1;
                }
            }
            __syncthreads();
        }

        // ---- Sinkhorn fused (u,v) x50 from registers, early exit on v fixed point ----
        for (int it = 1; it <= NSK; ++it) {
            float vv[MN];
            #pragma unroll
            for (int p = 0; p < 5; ++p) {
                unsigned w = svp[p];
                vv[2*p] = bflo(w); vv[2*p+1] = bfhi(w);
            }
            float a[MN];
            #pragma unroll
            for (int j = 0; j < MN; ++j) a[j] = 0.f;
            #pragma unroll
            for (int k = 0; k < RPT; ++k) {
                float R = 0.f;
                #pragma unroll
                for (int j = 0; j < MN; ++j) R += E[k][j] * vv[j];
                const float u = invn * __builtin_amdgcn_rcpf(R);
                uu[k] = u;
                #pragma unroll
                for (int j = 0; j < MN; ++j) a[j] += E[k][j] * u;
            }
            #pragma unroll
            for (int p = 0; p < 5; ++p) sPp[tid * 7 + p] = packbf(a[2*p], a[2*p+1]);
            __syncthreads();
            if (tid < 320) {
                const int p = tid >> 6, c = tid & 63;
                float s0 = 0.f, s1 = 0.f;
                #pragma unroll
                for (int kk = 0; kk < NW; ++kk) {
                    unsigned w = sPp[(c + (kk << 6)) * 7 + p];
                    s0 += bflo(w); s1 += bfhi(w);
                }
                #pragma unroll
                for (int d = 32; d; d >>= 1) { s0 += __shfl_xor(s0, d); s1 += __shfl_xor(s1, d); }
                if (c == 0) {
                    float v0 = sq[2*p] / s0, v1 = sq[2*p+1] / s1;
                    float o0 = sVf[2*p],    o1 = sVf[2*p+1];
                    sCv[p] = (__builtin_fabsf(v0 - o0) <= 2e-4f * v0 &&
                              __builtin_fabsf(v1 - o1) <= 2e-4f * v1) ? 1.f : 0.f;
                    sVf[2*p] = v0; sVf[2*p+1] = v1;
                    svp[p] = packbf(v0, v1);
                }
            }
            __syncthreads();
            if (sCv[0] + sCv[1] + sCv[2] + sCv[3] + sCv[4] == 5.f) break;
        }

        // ---- dT phase: dd = u*E*v - T (E from regs); dots; planes <- dd(bf16) ----
        {
            float vv[MN];
            #pragma unroll
            for (int p = 0; p < 5; ++p) {
                unsigned w = svp[p];
                vv[2*p] = bflo(w); vv[2*p+1] = bfhi(w);
            }
            float sMdT = 0.f, sCdT = 0.f, sCTdT = 0.f;
            #pragma unroll
            for (int k = 0; k < RPT; ++k) {
                const int r = tid + k * TPB;
                const float cp = cp_[k];
                const size_t b5 = (size_t)r * 5;
                const float u = uu[k];
                float dd[MN];
                #pragma unroll
                for (int h = 0; h < 5; ++h) {
                    unsigned tw = Tb[b5 + h], cw = Cb[b5 + h];
                    float2 mv = *(const float2*)(Mb + (size_t)r * MN + 2*h);
                    float d0 = u * E[k][2*h]   * vv[2*h]   - bflo(tw);
                    float d1 = u * E[k][2*h+1] * vv[2*h+1] - bfhi(tw);
                    dd[2*h] = d0; dd[2*h+1] = d1;
                    sMdT  += mv.x * d0 + mv.y * d1;
                    sCdT  += (cp + scq[2*h]) * d0 + (cp + scq[2*h+1]) * d1;
                    sCTdT += bflo(cw) * d0 + bfhi(cw) * d1;
                }
                PL4x[r] = make_uint4(packbf(dd[0],dd[1]), packbf(dd[2],dd[3]),
                                     packbf(dd[4],dd[5]), packbf(dd[6],dd[7]));
                PL1x[r] = packbf(dd[8], dd[9]);
            }
            #pragma unroll
            for (int d = 32; d; d >>= 1) {
                sMdT  += __shfl_xor(sMdT, d);
                sCdT  += __shfl_xor(sCdT, d);
                sCTdT += __shfl_xor(sCTdT, d);
            }
            if ((tid & 63) == 0) {
                const int w = tid >> 6;
                sRed[w] = sMdT; sRed[NW + w] = sCdT; sRed[2*NW + w] = sCTdT;
            }
            __syncthreads();   // dots staged AND dd planes visible block-wide
            if (tid == 0) {
                float r0 = 0.f, r1 = 0.f, r2 = 0.f;
                for (int w = 0; w < NW; ++w) { r0 += sRed[w]; r1 += sRed[NW+w]; r2 += sRed[2*NW+w]; }
                sDots[0] = r0; sDots[1] = r1; sDots[2] = r2;
            }
            __syncthreads();   // protect sRed before SpMM re-stages into it
        }

        // ---- SpMM: D = C1 dT C2 (gather dd planes, degree-sorted rows); sA = <D,dd> ----
        {
            float dot = 0.f;
            #pragma unroll
            for (int k = 0; k < RPT; ++k) {
                const int r = permg[tid + k * TPB];   // wave gets equal-degree rows
                float y[MN];
                #pragma unroll
                for (int j = 0; j < MN; ++j) y[j] = 0.f;
                const int st = rowst[r], dg = degi[r];
                const unsigned short* cl = colix + st;
                int e = 0;
                for (; e + 2 <= dg; e += 2) {
                    const int j0 = cl[e], j1 = cl[e + 1];
                    uint4 qa = PL4x[j0]; unsigned ba = PL1x[j0];
                    uint4 qb = PL4x[j1]; unsigned bb = PL1x[j1];
                    y[0] += bflo(qa.x) + bflo(qb.x); y[1] += bfhi(qa.x) + bfhi(qb.x);
                    y[2] += bflo(qa.y) + bflo(qb.y); y[3] += bfhi(qa.y) + bfhi(qb.y);
                    y[4] += bflo(qa.z) + bflo(qb.z); y[5] += bfhi(qa.z) + bfhi(qb.z);
                    y[6] += bflo(qa.w) + bflo(qb.w); y[7] += bfhi(qa.w) + bfhi(qb.w);
                    y[8] += bflo(ba)   + bflo(bb);   y[9] += bfhi(ba)   + bfhi(bb);
                }
                if (e < dg) {
                    const int j0 = cl[e];
                    uint4 qa = PL4x[j0]; unsigned ba = PL1x[j0];
                    y[0] += bflo(qa.x); y[1] += bfhi(qa.x);
                    y[2] += bflo(qa.y); y[3] += bfhi(qa.y);
                    y[4] += bflo(qa.z); y[5] += bfhi(qa.z);
                    y[6] += bflo(qa.w); y[7] += bfhi(qa.w);
                    y[8] += bflo(ba);   y[9] += bfhi(ba);
                }
                uint4 q = PL4x[r]; unsigned b4 = PL1x[r];
                float dd[MN];
                dd[0]=bflo(q.x); dd[1]=bfhi(q.x); dd[2]=bflo(q.y); dd[3]=bfhi(q.y);
                dd[4]=bflo(q.z); dd[5]=bfhi(q.z); dd[6]=bflo(q.w); dd[7]=bfhi(q.w);
                dd[8]=bflo(b4);  dd[9]=bfhi(b4);
                #pragma unroll
                for (int h = 0; h < 5; ++h) {
                    float o0 = 0.f, o1 = 0.f;
                    #pragma unroll
                    for (int j = 0; j < MN; ++j) {
                        o0 += y[j] * sC2[j * MN + 2*h];
                        o1 += y[j] * sC2[j * MN + 2*h + 1];
                    }
                    dot += o0 * dd[2*h] + o1 * dd[2*h+1];
                    Db[(size_t)r * 5 + h] = packbf(o0, o1);
                }
            }
            #pragma unroll
            for (int d = 32; d; d >>= 1) dot += __shfl_xor(dot, d);
            if ((tid & 63) == 0) sRed[tid >> 6] = dot;
            __syncthreads();
            if (tid == 0) {
                float s = 0.f;
                for (int w = 0; w < NW; ++w) s += sRed[w];
                sDots[3] = s;
            }
            __syncthreads();
        }
    }

    // ---- F: final tau + objective (T,C,D from bf16 globals; dd from planes) ----
    if (tid == 0) {
        float a = -2.f * alpha * sDots[3];
        float b = oma * sDots[0] + alpha * (sDots[1] - 4.f * sDots[2]);
        float tau;
        if (a > 0.f) tau = fminf(fmaxf(-b / (2.f * a + 1e-16f), 0.f), 1.f);
        else         tau = (a + b < 0.f) ? 1.f : 0.f;
        sBC[0] = tau;
    }
    __syncthreads();
    {
        const float tau = sBC[0];
        float gw = 0.f, wass = 0.f;
        #pragma unroll
        for (int k = 0; k < RPT; ++k) {
            const int r = tid + k * TPB;
            const float cp = cp_[k];
            const size_t b5 = (size_t)r * 5;
            uint4 q = PL4x[r]; unsigned b4 = PL1x[r];
            float dd[MN];
            dd[0]=bflo(q.x); dd[1]=bfhi(q.x); dd[2]=bflo(q.y); dd[3]=bfhi(q.y);
            dd[4]=bflo(q.z); dd[5]=bfhi(q.z); dd[6]=bflo(q.w); dd[7]=bfhi(q.w);
            dd[8]=bflo(b4);  dd[9]=bfhi(b4);
            #pragma unroll
            for (int h = 0; h < 5; ++h) {
                unsigned tw = Tb[b5 + h], cw = Cb[b5 + h], Dw = Db[b5 + h];
                float2 mv = *(const float2*)(Mb + (size_t)r * MN + 2*h);
                float Tf0 = bflo(tw) + tau * dd[2*h];
                float Tf1 = bfhi(tw) + tau * dd[2*h+1];
                float Cf0 = bflo(cw) + tau * bflo(Dw);
                float Cf1 = bfhi(cw) + tau * bfhi(Dw);
                gw   += (cp + scq[2*h]   - 2.f * Cf0) * Tf0
                      + (cp + scq[2*h+1] - 2.f * Cf1) * Tf1;
                wass += mv.x * Tf0 + mv.y * Tf1;
            }
        }
        #pragma unroll
        for (int d = 32; d; d >>= 1) {
            gw   += __shfl_xor(gw, d);
            wass += __shfl_xor(wass, d);
        }
        if ((tid & 63) == 0) { sRed[tid >> 6] = gw; sRed[NW + (tid >> 6)] = wass; }
        __syncthreads();
        if (tid == 0) {
            float g = 0.f, ws = 0.f;
            for (int w = 0; w < NW; ++w) { g += sRed[w]; ws += sRed[NW + w]; }
            out[t] = oma * ws + alpha * g;
        }
    }
}

extern "C" void kernel_launch(void* const* d_in, const int* in_sizes, int n_in,
                              void* d_out, int out_size, void* d_ws, size_t ws_size,
                              hipStream_t stream) {
    const float* x   = (const float*)d_in[0];
    const void*  ei  = d_in[1];
    const float* tpl = (const float*)d_in[2];
    const float* tfp = (const float*)d_in[3];
    const float* q0  = (const float*)d_in[4];
    const float* a0  = (const float*)d_in[5];
    float* outp = (float*)d_out;
    float* Wp   = (float*)d_ws;
    (void)hipFuncSetAttribute(reinterpret_cast<const void*>(&tfgw_kernel),
                              hipFuncAttributeMaxDynamicSharedMemorySize, LDS_DYN);
    void* args[] = { &x, &ei, &tpl, &tfp, &q0, &a0, &outp, &Wp };
    hipLaunchCooperativeKernel(reinterpret_cast<const void*>(&tfgw_kernel),
                               dim3(NBLK), dim3(TPB), args, LDS_DYN, stream);
}